// Round 13
// baseline (402.626 us; speedup 1.0000x reference)
//
#include <hip/hip_runtime.h>

typedef unsigned short u16;
typedef __attribute__((ext_vector_type(8))) short short8;   // 8 bf16 = 4 VGPRs (MFMA A/B frag)
typedef __attribute__((ext_vector_type(4))) float f32x4;    // MFMA C/D frag

#define T_SEQ 4096
#define DMODEL 1024
#define NH 16
#define DKH 64
#define KPROJ 256

// ---------- bf16 helpers (bit-level, RNE) ----------
__device__ __forceinline__ u16 f2bf(float f) {
  union { float f; unsigned u; } v; v.f = f;
  unsigned r = v.u + 0x7FFFu + ((v.u >> 16) & 1u);
  return (u16)(r >> 16);
}
__device__ __forceinline__ float bf2f(u16 h) {
  union { unsigned u; float f; } v; v.u = ((unsigned)h) << 16; return v.f;
}
// pack 2 f32 -> 2 bf16 in one u32 (lo = a, hi = b); gfx950 HW RNE
__device__ __forceinline__ unsigned cvt_pk_bf16(float a, float b) {
  unsigned r;
  asm("v_cvt_pk_bf16_f32 %0, %1, %2" : "=v"(r) : "v"(a), "v"(b));
  return r;
}

// ---------- async global->LDS, 16B/lane; LDS base wave-uniform, lane i lands at +16*i ----------
__device__ __forceinline__ void gl2lds16(const u16* g, u16* l) {
  __builtin_amdgcn_global_load_lds(
      (const __attribute__((address_space(1))) unsigned int*)g,
      (__attribute__((address_space(3))) unsigned int*)(unsigned int)(unsigned long long)l,
      16, 0, 0);
}

#define SBAR() __builtin_amdgcn_sched_barrier(0)

// ---------- dtype sniffer: fp32 read as u16 pairs -> ~0.4% NaN/Inf bf16 patterns ----------
__global__ void sniff_dtype(const u16* __restrict__ x, int* __restrict__ flag) {
  int c = 0;
  for (int i = threadIdx.x; i < 8192; i += 64)
    if ((x[2 * i] & 0x7F80) == 0x7F80) c++;
#pragma unroll
  for (int m = 1; m < 64; m <<= 1) c += __shfl_xor(c, m);
  if (threadIdx.x == 0) *flag = (c > 0) ? 1 : 0;   // 1 = inputs are float32
}

// ---------- x: tiled transpose + convert, FUSED row-major bf16 copy ----------
__global__ void transpose_x(const void* __restrict__ in, u16* __restrict__ outT,
                            u16* __restrict__ outR, const int* __restrict__ flag) {
  __shared__ u16 tile[32][33];
  const bool f32 = (*flag != 0);
  const size_t zoff = (size_t)blockIdx.z * T_SEQ * DMODEL;
  const int c0 = blockIdx.x * 32, r0 = blockIdx.y * 32;
  for (int i = threadIdx.y; i < 32; i += 8) {
    const size_t idx = zoff + (size_t)(r0 + i) * DMODEL + c0 + threadIdx.x;
    const u16 v = f32 ? f2bf(((const float*)in)[idx]) : ((const u16*)in)[idx];
    tile[i][threadIdx.x] = v;
    outR[idx] = v;
  }
  __syncthreads();
  for (int i = threadIdx.y; i < 32; i += 8)
    outT[zoff + (size_t)(c0 + i) * T_SEQ + r0 + threadIdx.x] = tile[threadIdx.x][i];
}

// ---------- batched tiled transpose+convert, up to 4 distinct inputs selected by z ----------
__global__ void transpose_cvt4(const void* __restrict__ p0, const void* __restrict__ p1,
                               const void* __restrict__ p2, const void* __restrict__ p3,
                               u16* __restrict__ out, int R, int C, const int* __restrict__ flag) {
  __shared__ u16 tile[32][33];
  const bool f32 = (*flag != 0);
  const int z = blockIdx.z;
  const void* in = (z == 0) ? p0 : (z == 1) ? p1 : (z == 2) ? p2 : p3;
  const size_t zoff = (size_t)z * R * C;
  const int c0 = blockIdx.x * 32, r0 = blockIdx.y * 32;
  for (int i = threadIdx.y; i < 32; i += 8) {
    const size_t idx = (size_t)(r0 + i) * C + c0 + threadIdx.x;
    tile[i][threadIdx.x] = f32 ? f2bf(((const float*)in)[idx]) : ((const u16*)in)[idx];
  }
  __syncthreads();
  for (int i = threadIdx.y; i < 32; i += 8)
    out[zoff + (size_t)(c0 + i) * R + r0 + threadIdx.x] = tile[threadIdx.x][i];
}

// ---------- split-K reduce: xE[b][j] = bf16(sum_s P[(b*4+s)*stride + j]) ----------
__global__ void reduce_splitk(const float* __restrict__ P, u16* __restrict__ out) {
  const int b = blockIdx.y;
  const int j = (blockIdx.x * 256 + threadIdx.x) * 8;
  const float* p = P + (size_t)b * 4 * 524288 + j;
  float acc[8] = {};
#pragma unroll
  for (int s = 0; s < 4; ++s) {
    const float4 v0 = *(const float4*)(p + (size_t)s * 524288);
    const float4 v1 = *(const float4*)(p + (size_t)s * 524288 + 4);
    acc[0] += v0.x; acc[1] += v0.y; acc[2] += v0.z; acc[3] += v0.w;
    acc[4] += v1.x; acc[5] += v1.y; acc[6] += v1.z; acc[7] += v1.w;
  }
  union { u16 s[8]; short8 v; } o;
#pragma unroll
  for (int k = 0; k < 8; ++k) o.s[k] = f2bf(acc[k]);
  *(short8*)(out + (size_t)b * 524288 + j) = o.v;
}

// ---------- 128x128-tile GEMM (small/batched shapes): r9 3-buffer pipeline, PASSED ----------
template <int MODE>
__global__ void __launch_bounds__(256) gemm_bt(const u16* __restrict__ A0, const u16* __restrict__ Bt0,
                                               const void* __restrict__ bias, void* __restrict__ Cv,
                                               const int* __restrict__ flag, int M, int N, int K,
                                               int ldA, int ldB, size_t sA, size_t sB, size_t sC) {
  __shared__ __align__(16) u16 As[3][128 * 32];
  __shared__ __align__(16) u16 Bs[3][128 * 32];

  const int gx = gridDim.x, gy = gridDim.y;
  const int gxy = gx * gy;
  const int nwg = gxy * gridDim.z;
  int lin = (blockIdx.z * gy + blockIdx.y) * gx + blockIdx.x;
  if ((nwg & 7) == 0) lin = (lin & 7) * (nwg >> 3) + (lin >> 3);
  const int bz = lin / gxy;
  const int rem = lin - bz * gxy;
  const int by = rem / gx;
  const int bx = rem - by * gx;

  const int z = bz;
  const int bb = (MODE == 2) ? (z >> 2) : z;
  const int kstart = (MODE == 2) ? ((z & 3) * K) : 0;
  const u16* A = A0 + (size_t)bb * sA;
  const u16* Bt = Bt0 + (size_t)bb * sB;
  const int tid = threadIdx.x;
  const int wid = tid >> 6, lane = tid & 63;
  const int wm = wid >> 1, wn = wid & 1;
  const int quad = lane >> 4, l16 = lane & 15;
  const int m0 = by * 128, n0 = bx * 128;

  const int srow = lane >> 2;
  const int scol = (((lane & 3) ^ ((lane >> 3) & 3)) * 8);   // elements

  const u16* Ag = A + (size_t)(m0 + srow) * ldA + scol + kstart;
  const u16* Bg = Bt + (size_t)(n0 + srow) * ldB + scol + kstart;

  f32x4 acc[4][4] = {};

  auto stage = [&](int buf, int k0) {
#pragma unroll
    for (int r = 0; r < 2; ++r) {
      const int rowb = r * 64 + wid * 16;               // wave-uniform LDS base
      gl2lds16(Ag + (size_t)rowb * ldA + k0, &As[buf][rowb * 32]);
      gl2lds16(Bg + (size_t)rowb * ldB + k0, &Bs[buf][rowb * 32]);
    }
  };

  const int nI = K >> 5;
  stage(0, 0);
  stage(1, 32);

  const int rslot = (quad ^ ((l16 >> 1) & 3)) * 8;      // elements

  int cur = 0;                                          // t % 3
  for (int t = 0; t < nI; ++t) {
    if (t + 1 < nI) {
      asm volatile("s_waitcnt lgkmcnt(0) vmcnt(4)" ::: "memory");
    } else {
      asm volatile("s_waitcnt lgkmcnt(0) vmcnt(0)" ::: "memory");
    }
    SBAR();
    __builtin_amdgcn_s_barrier();                       // tile-t DMA globally done; buf free
    SBAR();

    const int nxt = (cur + 2 >= 3) ? (cur - 1) : (cur + 2);
    if (t + 2 < nI) stage(nxt, (t + 2) << 5);           // overwrite buffer read at t-1

    short8 a[4], b[4];
#pragma unroll
    for (int mi = 0; mi < 4; ++mi)
      a[mi] = *(const short8*)(&As[cur][(wm * 64 + mi * 16 + l16) * 32 + rslot]);
#pragma unroll
    for (int ni = 0; ni < 4; ++ni)
      b[ni] = *(const short8*)(&Bs[cur][(wn * 64 + ni * 16 + l16) * 32 + rslot]);
    __builtin_amdgcn_s_setprio(1);
#pragma unroll
    for (int mi = 0; mi < 4; ++mi)
#pragma unroll
      for (int ni = 0; ni < 4; ++ni)
        acc[mi][ni] = __builtin_amdgcn_mfma_f32_16x16x32_bf16(a[mi], b[ni], acc[mi][ni], 0, 0, 0);
    __builtin_amdgcn_s_setprio(0);

    cur = (cur + 1 >= 3) ? 0 : (cur + 1);
  }

  const bool f32out = (MODE == 1) && (*flag != 0);
  float* Pz = (MODE == 2) ? ((float*)Cv + (size_t)z * M * N) : nullptr;
#pragma unroll
  for (int mi = 0; mi < 4; ++mi) {
#pragma unroll
    for (int ni = 0; ni < 4; ++ni) {
      const int mloc = wm * 64 + mi * 16 + quad * 4;
      const int n = n0 + wn * 64 + ni * 16 + l16;
      float badd = 0.0f;
      if (MODE == 1)
        badd = f32out ? ((const float*)bias)[n] : bf2f(((const u16*)bias)[n]);
#pragma unroll
      for (int r = 0; r < 4; ++r) {
        if (MODE == 2) {
          Pz[(size_t)(m0 + mloc + r) * N + n] = acc[mi][ni][r];
        } else {
          const size_t oi = (size_t)bb * sC + (size_t)(m0 + mloc + r) * N + n;
          if (f32out) ((float*)Cv)[oi] = acc[mi][ni][r] + badd;
          else        ((u16*)Cv)[oi]  = f2bf(acc[mi][ni][r] + badd);
        }
      }
    }
  }
}

// ---------- 128x256-tile GEMM, BK=32, 512 threads (8 waves 2Mx4N), 2 LDS buffers ----------
// r11-PASSED schedule skeleton, resized BM=256->128 for occupancy: grid 512 blocks =
// 2+/CU (vs 256 = 1/CU), LDS 48 KB -> up to 3 blocks/CU. Inter-block overlap hides the
// stage+barrier drain (m114 mechanism) that 1-block/CU exposed.
//   prologue: stage(0,t0), stage(1,t1)                  (6 loads/wave outstanding, 3/stage)
//   iter t:   vmcnt(3) [0 on last]  -> own tile-t loads done
//             s_barrier              -> all waves' tile-t DMA landed
//             ds_read buf[t&1] (swizzled) + 16 MFMA/wave (4Mx4N frags)
//             lgkmcnt(0); s_barrier  -> everyone done reading buf[t&1]
//             stage(t&1, t+2)        -> overwrite freed buffer
// Swizzle = r9/r11 proven pair (0 conflicts, counter-verified).
// Requires K%32==0, M%128==0, N%256==0. MODE 0: bf16 out; MODE 1: +bias, fp32/bf16 per *flag.
template <int MODE>
__global__ void __launch_bounds__(512, 2) gemm256(const u16* __restrict__ A,
                                                  const u16* __restrict__ Bt,
                                                  const void* __restrict__ bias,
                                                  void* __restrict__ Cv,
                                                  const int* __restrict__ flag,
                                                  int M, int N, int K) {
  __shared__ __align__(16) u16 As[2][128 * 32];        // 2 x 8 KB
  __shared__ __align__(16) u16 Bs[2][256 * 32];        // 2 x 16 KB -> 48 KB total

  const int gx = gridDim.x;                             // N/256
  const int nwg = gx * gridDim.y;
  int lin = blockIdx.y * gx + blockIdx.x;
  if ((nwg & 7) == 0) lin = (lin & 7) * (nwg >> 3) + (lin >> 3);
  const int by = lin / gx;
  const int bx = lin - by * gx;
  const int m0 = by * 128, n0 = bx * 256;

  const int tid = threadIdx.x;
  const int wid = tid >> 6, lane = tid & 63;
  const int wm = wid >> 2, wn = wid & 3;                // 2 x 4 wave grid; wave = 64x64 out
  const int quad = lane >> 4, l16 = lane & 15;

  // staging: lane -> row (lane>>2) within a 16-row group, 16B slot (lane&3);
  // source col pre-swizzled by (row>>1)&3 = (lane>>3)&3 (r9/r11-proven pattern)
  const int srcswz = ((lane & 3) ^ ((lane >> 3) & 3)) * 8;   // elements
  const u16* AgS = A + (size_t)(m0 + wid * 16 + (lane >> 2)) * K + srcswz;
  const u16* BgS = Bt + (size_t)(n0 + wid * 16 + (lane >> 2)) * K + srcswz;

  auto stage = [&](int buf, int tk) {
    const int kof = tk * 32;
    gl2lds16(AgS + kof, &As[buf][(wid * 16) * 32]);                       // A: 128 rows, 1 issue
#pragma unroll
    for (int e = 0; e < 2; ++e)                                           // B: 256 rows, 2 issues
      gl2lds16(BgS + (size_t)(e * 128) * K + kof, &Bs[buf][(e * 128 + wid * 16) * 32]);
  };

  f32x4 acc[4][4] = {};
  const int nT = K >> 5;

  stage(0, 0);
  stage(1, 1);

  const int rslot = (quad ^ ((l16 >> 1) & 3)) * 8;      // elements (0 conflicts, verified)

  for (int t = 0; t < nT; ++t) {
    const int cur = t & 1;
    if (t + 1 < nT) {
      asm volatile("s_waitcnt vmcnt(3)" ::: "memory");  // own tile-t loads (3) done
    } else {
      asm volatile("s_waitcnt vmcnt(0)" ::: "memory");  // last tile: drain all
    }
    SBAR();
    __builtin_amdgcn_s_barrier();                       // all waves' tile-t DMA landed
    SBAR();

    short8 a[4], b[4];
#pragma unroll
    for (int mf = 0; mf < 4; ++mf)
      a[mf] = *(const short8*)(&As[cur][(wm * 64 + mf * 16 + l16) * 32 + rslot]);
#pragma unroll
    for (int nf = 0; nf < 4; ++nf)
      b[nf] = *(const short8*)(&Bs[cur][(wn * 64 + nf * 16 + l16) * 32 + rslot]);
    __builtin_amdgcn_s_setprio(1);
#pragma unroll
    for (int mf = 0; mf < 4; ++mf)
#pragma unroll
      for (int nf = 0; nf < 4; ++nf)
        acc[mf][nf] = __builtin_amdgcn_mfma_f32_16x16x32_bf16(a[mf], b[nf], acc[mf][nf], 0, 0, 0);
    __builtin_amdgcn_s_setprio(0);

    asm volatile("s_waitcnt lgkmcnt(0)" ::: "memory");  // my ds_reads of buf(cur) done
    SBAR();
    __builtin_amdgcn_s_barrier();                       // everyone done reading buf(cur)
    if (t + 2 < nT) stage(cur, t + 2);                  // overwrite freed buffer
  }

  const bool f32out = (MODE == 1) && (*flag != 0);
#pragma unroll
  for (int mf = 0; mf < 4; ++mf) {
#pragma unroll
    for (int nf = 0; nf < 4; ++nf) {
      const int row = m0 + wm * 64 + mf * 16 + quad * 4;
      const int col = n0 + wn * 64 + nf * 16 + l16;
      float badd = 0.0f;
      if (MODE == 1)
        badd = f32out ? ((const float*)bias)[col] : bf2f(((const u16*)bias)[col]);
#pragma unroll
      for (int r = 0; r < 4; ++r) {
        const size_t oi = (size_t)(row + r) * N + col;
        if (MODE == 1) {
          if (f32out) ((float*)Cv)[oi] = acc[mf][nf][r] + badd;
          else        ((u16*)Cv)[oi]  = f2bf(acc[mf][nf][r] + badd);
        } else {
          ((u16*)Cv)[oi] = f2bf(acc[mf][nf][r]);
        }
      }
    }
  }
}

// ---------- fused scores+softmax+ctx, block-cooperative K/V LDS staging (r7, proven) ----------
__global__ void __launch_bounds__(256, 2) attn_fused(const u16* Q, const u16* __restrict__ Kp,
                                                     const u16* __restrict__ VpT, u16* Ctx) {
  __shared__ __align__(16) u16 Ks[KPROJ * DKH];     // [256][64] u16, swizzled cols
  __shared__ __align__(16) u16 Vs[DKH * KPROJ];     // [64][256] u16, swizzled cols
  __shared__ __align__(16) u16 Ps[4 * 32 * 36];
  __shared__ __align__(16) float invS[4 * 32];

  int lin = blockIdx.y * gridDim.x + blockIdx.x;    // grid (32, 64): 2048 blocks
  lin = (lin & 7) * 256 + (lin >> 3);               // XCD x -> bh in [8x, 8x+8)
  const int bx = lin & 31;
  const int bh = lin >> 5;
  const int b = bh >> 4, h = bh & 15;
  const int tid = threadIdx.x, wid = tid >> 6, lane = tid & 63;
  const int quad = lane >> 4, l16 = lane & 15;
  const int t0 = bx * 128 + wid * 32;
  const u16* Qb = Q + ((size_t)b * T_SEQ + t0) * DMODEL + h * DKH;
  const u16* Kpb = Kp + (size_t)b * (KPROJ * DMODEL) + h * DKH;
  const u16* Vpb = VpT + (size_t)b * (DMODEL * KPROJ) + (size_t)(h * DKH) * KPROJ;
  u16* PsW = Ps + wid * (32 * 36);
  float* invW = invS + wid * 32;

  {
    const int srow = lane >> 3;                          // 0..7 within issue
    const int scolb = ((lane & 7) * 16) ^ ((srow & 7) << 4);   // inverse swizzle on source
#pragma unroll
    for (int i = 0; i < 8; ++i) {
      const int rbase = wid * 64 + i * 8;
      gl2lds16(Kpb + (size_t)(rbase + srow) * DMODEL + (scolb >> 1), Ks + rbase * DKH);
    }
    const int vrow = lane >> 5;                          // 0..1 within issue
#pragma unroll
    for (int j = 0; j < 8; ++j) {
      const int dbase = wid * 16 + j * 2;
      const int d = dbase + vrow;
      const int vcolb = ((lane & 31) * 16) ^ ((d & 7) << 4);
      gl2lds16(Vpb + (size_t)d * KPROJ + (vcolb >> 1), Vs + dbase * KPROJ);
    }
  }

  short8 q[2][2];
#pragma unroll
  for (int kk = 0; kk < 2; ++kk) {
    q[kk][0] = *(const short8*)(Qb + (size_t)l16 * DMODEL + kk * 32 + quad * 8);
    q[kk][1] = *(const short8*)(Qb + (size_t)(16 + l16) * DMODEL + kk * 32 + quad * 8);
  }

  __syncthreads();   // drains vmcnt incl. LDS-DMA; K/V ready

  f32x4 c0[4] = {}, c1[4] = {};
  float sm0 = 0.0f, sm1 = 0.0f;
  const float sc = 0.125f * 1.44269504f;   // 1/sqrt(64) * log2(e)

#pragma unroll
  for (int kt = 0; kt < 8; ++kt) {
    short8 kf[2][2];
#pragma unroll
    for (int m = 0; m < 2; ++m)
#pragma unroll
      for (int k2 = 0; k2 < 2; ++k2) {
        const int row = kt * 32 + m * 16 + l16;
        const int off = ((k2 * 64 + quad * 16) ^ ((row & 7) << 4)) >> 1;
        kf[m][k2] = *(const short8*)(Ks + row * DKH + off);
      }
    f32x4 st[2][2] = {};
    __builtin_amdgcn_s_setprio(1);
#pragma unroll
    for (int m = 0; m < 2; ++m)
#pragma unroll
      for (int k2 = 0; k2 < 2; ++k2) {
        st[m][0] = __builtin_amdgcn_mfma_f32_16x16x32_bf16(kf[m][k2], q[k2][0], st[m][0], 0, 0, 0);
        st[m][1] = __builtin_amdgcn_mfma_f32_16x16x32_bf16(kf[m][k2], q[k2][1], st[m][1], 0, 0, 0);
      }
    __builtin_amdgcn_s_setprio(0);

#pragma unroll
    for (int m = 0; m < 2; ++m) {
      const float a0 = exp2f(st[m][0][0] * sc), a1 = exp2f(st[m][0][1] * sc);
      const float a2 = exp2f(st[m][0][2] * sc), a3 = exp2f(st[m][0][3] * sc);
      const float b0 = exp2f(st[m][1][0] * sc), b1 = exp2f(st[m][1][1] * sc);
      const float b2 = exp2f(st[m][1][2] * sc), b3 = exp2f(st[m][1][3] * sc);
      sm0 += (a0 + a1) + (a2 + a3);
      sm1 += (b0 + b1) + (b2 + b3);
      *(uint2*)(PsW + l16 * 36 + m * 16 + quad * 4) =
          make_uint2(cvt_pk_bf16(a0, a1), cvt_pk_bf16(a2, a3));
      *(uint2*)(PsW + (16 + l16) * 36 + m * 16 + quad * 4) =
          make_uint2(cvt_pk_bf16(b0, b1), cvt_pk_bf16(b2, b3));
    }

    short8 vf[4];
#pragma unroll
    for (int ni = 0; ni < 4; ++ni) {
      const int d = ni * 16 + l16;
      const int off = ((kt * 64 + quad * 16) ^ ((d & 7) << 4)) >> 1;
      vf[ni] = *(const short8*)(Vs + d * KPROJ + off);
    }
    short8 pa0 = *(const short8*)(PsW + (size_t)l16 * 36 + quad * 8);
    short8 pa1 = *(const short8*)(PsW + (size_t)(16 + l16) * 36 + quad * 8);
    __builtin_amdgcn_s_setprio(1);
#pragma unroll
    for (int ni = 0; ni < 4; ++ni) {
      c0[ni] = __builtin_amdgcn_mfma_f32_16x16x32_bf16(pa0, vf[ni], c0[ni], 0, 0, 0);
      c1[ni] = __builtin_amdgcn_mfma_f32_16x16x32_bf16(pa1, vf[ni], c1[ni], 0, 0, 0);
    }
    __builtin_amdgcn_s_setprio(0);
  }

  sm0 += __shfl_xor(sm0, 16); sm0 += __shfl_xor(sm0, 32);
  sm1 += __shfl_xor(sm1, 16); sm1 += __shfl_xor(sm1, 32);
  if (quad == 0) {
    invW[l16] = 1.0f / sm0;
    invW[16 + l16] = 1.0f / sm1;
  }

  const float4 iv0 = *(const float4*)(invW + quad * 4);
  const float4 iv1 = *(const float4*)(invW + 16 + quad * 4);
  const float ivr0[4] = {iv0.x, iv0.y, iv0.z, iv0.w};
  const float ivr1[4] = {iv1.x, iv1.y, iv1.z, iv1.w};
#pragma unroll
  for (int ni = 0; ni < 4; ++ni)
#pragma unroll
    for (int r = 0; r < 4; ++r) {
      Ctx[((size_t)b * T_SEQ + t0 + quad * 4 + r) * DMODEL + h * DKH + ni * 16 + l16] =
          f2bf(c0[ni][r] * ivr0[r]);
      Ctx[((size_t)b * T_SEQ + t0 + 16 + quad * 4 + r) * DMODEL + h * DKH + ni * 16 + l16] =
          f2bf(c1[ni][r] * ivr1[r]);
    }
}

extern "C" void kernel_launch(void* const* d_in, const int* in_sizes, int n_in,
                              void* d_out, int out_size, void* d_ws, size_t ws_size,
                              hipStream_t stream) {
  (void)in_sizes; (void)n_in; (void)out_size; (void)ws_size;

  int* flag = (int*)d_ws;
  u16* base = (u16*)d_ws + 16;
  const size_t WSZ = 1048576;        // 1024*1024
  const size_t XSZ = 16777216;       // 4*4096*1024
  u16* wqT   = base + 0 * WSZ;
  u16* wkT   = base + 1 * WSZ;
  u16* wvT   = base + 2 * WSZ;
  u16* woT   = base + 3 * WSZ;
  u16* ekevT = base + 4 * WSZ;       // [ekT(256x4096); evT(256x4096)]
  u16* xT    = base + 6 * WSZ;       // (4, 1024, 4096)
  u16* xE    = xT + XSZ;             // (4, 512, 1024): rows 0-255 = Ek^T x, 256-511 = Ev^T x
  u16* Kp    = xE + 4 * 524288;      // (4, 256, 1024)
  u16* VpT   = Kp + 4 * 262144;      // (4, 1024, 256)
  u16* Q     = VpT + 4 * 262144;     // (4, 4096, 1024); also split-K partial buffer (32 MiB), then ctx
  u16* xbf   = (u16*)d_out;          // x bf16 scratch in d_out (dead before final gemm)
  float* xEp = (float*)Q;            // 16 blocks of 512*1024 fp32 partials (exactly Q's 32 MiB)

  sniff_dtype<<<1, 64, 0, stream>>>((const u16*)d_in[0], flag);

  dim3 tb(32, 8);
  // x: transpose (xT) + fused row-major bf16 copy (xbf)
  transpose_x<<<dim3(32, 128, 4), tb, 0, stream>>>(d_in[0], xT, xbf, flag);
  // 4 weight transposes in one launch (outputs contiguous at base+z*WSZ)
  transpose_cvt4<<<dim3(32, 32, 4), tb, 0, stream>>>(d_in[1], d_in[2], d_in[3], d_in[6],
                                                     wqT, 1024, 1024, flag);
  // Ek/Ev transposes in one launch (outputs contiguous)
  transpose_cvt4<<<dim3(8, 128, 2), tb, 0, stream>>>(d_in[4], d_in[5], nullptr, nullptr,
                                                     ekevT, 4096, 256, flag);

  // xE[b] = [Ek;Ev]^T @ x[b], split-K x4: z = b*4+s, each K-chunk 1024
  gemm_bt<2><<<dim3(8, 4, 16), 256, 0, stream>>>(ekevT, xT, nullptr, xEp, flag,
                                                 512, 1024, 1024, 4096, 4096,
                                                 0, (size_t)DMODEL * T_SEQ, 0);
  reduce_splitk<<<dim3(256, 4), 256, 0, stream>>>(xEp, xE);

  // Kp[b] = xEk[b] @ Wk -> (256 x 1024)
  gemm_bt<0><<<dim3(8, 2, 4), 256, 0, stream>>>(xE, wkT, nullptr, Kp, flag,
                                                256, 1024, 1024, 1024, 1024, 524288, 0, 262144);
  // Vp^T[b] = Wv^T @ xEv[b]^T -> (1024 x 256)
  gemm_bt<0><<<dim3(2, 8, 4), 256, 0, stream>>>(wvT, xE + 262144, nullptr, VpT, flag,
                                                1024, 256, 1024, 1024, 1024, 0, 524288, 262144);
  // Q = x @ Wq -> (16384 x 1024), 128x256-tile pipeline, 512 blocks (2+/CU)
  gemm256<0><<<dim3(4, 128), 512, 0, stream>>>(xbf, wqT, nullptr, Q, flag, 16384, 1024, 1024);

  attn_fused<<<dim3(32, 64), 256, 0, stream>>>(Q, Kp, VpT, Q /*ctx in-place*/);

  // out = ctx @ Wo + bo (fp32 or bf16 per flag), 128x256-tile pipeline
  gemm256<1><<<dim3(4, 128), 512, 0, stream>>>(Q, woT, d_in[7], d_out, flag, 16384, 1024, 1024);
}

// Round 14
// 387.380 us; speedup vs baseline: 1.0394x; 1.0394x over previous
//
#include <hip/hip_runtime.h>

typedef unsigned short u16;
typedef __attribute__((ext_vector_type(8))) short short8;   // 8 bf16 = 4 VGPRs (MFMA A/B frag)
typedef __attribute__((ext_vector_type(4))) float f32x4;    // MFMA C/D frag

#define T_SEQ 4096
#define DMODEL 1024
#define NH 16
#define DKH 64
#define KPROJ 256

// ---------- bf16 helpers (bit-level, RNE) ----------
__device__ __forceinline__ u16 f2bf(float f) {
  union { float f; unsigned u; } v; v.f = f;
  unsigned r = v.u + 0x7FFFu + ((v.u >> 16) & 1u);
  return (u16)(r >> 16);
}
__device__ __forceinline__ float bf2f(u16 h) {
  union { unsigned u; float f; } v; v.u = ((unsigned)h) << 16; return v.f;
}
// pack 2 f32 -> 2 bf16 in one u32 (lo = a, hi = b); gfx950 HW RNE
__device__ __forceinline__ unsigned cvt_pk_bf16(float a, float b) {
  unsigned r;
  asm("v_cvt_pk_bf16_f32 %0, %1, %2" : "=v"(r) : "v"(a), "v"(b));
  return r;
}

// ---------- async global->LDS, 16B/lane; LDS base wave-uniform, lane i lands at +16*i ----------
__device__ __forceinline__ void gl2lds16(const u16* g, u16* l) {
  __builtin_amdgcn_global_load_lds(
      (const __attribute__((address_space(1))) unsigned int*)g,
      (__attribute__((address_space(3))) unsigned int*)(unsigned int)(unsigned long long)l,
      16, 0, 0);
}

#define SBAR() __builtin_amdgcn_sched_barrier(0)

// ---------- dtype sniffer: fp32 read as u16 pairs -> ~0.4% NaN/Inf bf16 patterns ----------
__global__ void sniff_dtype(const u16* __restrict__ x, int* __restrict__ flag) {
  int c = 0;
  for (int i = threadIdx.x; i < 8192; i += 64)
    if ((x[2 * i] & 0x7F80) == 0x7F80) c++;
#pragma unroll
  for (int m = 1; m < 64; m <<= 1) c += __shfl_xor(c, m);
  if (threadIdx.x == 0) *flag = (c > 0) ? 1 : 0;   // 1 = inputs are float32
}

// ---------- 64x64-tile transpose of x, 16B/lane, FUSED row-major bf16 copy ----------
// outT[z][c][r] = bf16(in[z][r][c]); outR[z][r][c] = bf16(in[z][r][c]).
// Load: float4/ushort4 (256B contiguous per 16 lanes); LDS u16[64][72] (stride-36-u16
// pattern, 0-conflict precedent from attn Ps); store short8 (128B contiguous per 8 lanes).
__global__ void __launch_bounds__(256) transpose64_x(const void* __restrict__ in,
                                                     u16* __restrict__ outT,
                                                     u16* __restrict__ outR,
                                                     const int* __restrict__ flag) {
  __shared__ u16 tile[64][72];
  const bool f32 = (*flag != 0);
  const size_t zoff = (size_t)blockIdx.z * T_SEQ * DMODEL;
  const int c0 = blockIdx.x * 64, r0 = blockIdx.y * 64;
  const int t = threadIdx.x;
  const int r_in = t >> 4, c4 = t & 15;          // load: row r_in+i*16, col c4*4
#pragma unroll
  for (int i = 0; i < 4; ++i) {
    const int row = r0 + i * 16 + r_in;
    const size_t base = zoff + (size_t)row * DMODEL + c0 + c4 * 4;
    u16 b[4];
    if (f32) {
      const float4 v = *(const float4*)((const float*)in + base);
      b[0] = f2bf(v.x); b[1] = f2bf(v.y); b[2] = f2bf(v.z); b[3] = f2bf(v.w);
    } else {
      const ushort4 v = *(const ushort4*)((const u16*)in + base);
      b[0] = v.x; b[1] = v.y; b[2] = v.z; b[3] = v.w;
    }
    *(uint2*)(outR + base) = make_uint2((unsigned)b[0] | ((unsigned)b[1] << 16),
                                        (unsigned)b[2] | ((unsigned)b[3] << 16));
#pragma unroll
    for (int j = 0; j < 4; ++j) tile[c4 * 4 + j][i * 16 + r_in] = b[j];
  }
  __syncthreads();
  const int c_loc = t >> 3, r8 = t & 7;          // store: col c_loc+i*32, rows r8*8..+7
#pragma unroll
  for (int i = 0; i < 2; ++i) {
    const int c = c_loc + i * 32;
    *(short8*)(outT + zoff + (size_t)(c0 + c) * T_SEQ + r0 + r8 * 8) =
        *(const short8*)(&tile[c][r8 * 8]);
  }
}

// ---------- 64x64-tile transpose+cvt, up to 4 distinct inputs selected by z, 16B/lane ----------
// out[z][c][r] = bf16(pz[r][c]); out blocks contiguous at stride R*C.
__global__ void __launch_bounds__(256) transpose64_m(const void* __restrict__ p0,
                                                     const void* __restrict__ p1,
                                                     const void* __restrict__ p2,
                                                     const void* __restrict__ p3,
                                                     u16* __restrict__ out, int R, int C,
                                                     const int* __restrict__ flag) {
  __shared__ u16 tile[64][72];
  const bool f32 = (*flag != 0);
  const int z = blockIdx.z;
  const void* in = (z == 0) ? p0 : (z == 1) ? p1 : (z == 2) ? p2 : p3;
  const size_t zoff = (size_t)z * R * C;
  const int c0 = blockIdx.x * 64, r0 = blockIdx.y * 64;
  const int t = threadIdx.x;
  const int r_in = t >> 4, c4 = t & 15;
#pragma unroll
  for (int i = 0; i < 4; ++i) {
    const int row = r0 + i * 16 + r_in;
    const size_t base = (size_t)row * C + c0 + c4 * 4;
    u16 b[4];
    if (f32) {
      const float4 v = *(const float4*)((const float*)in + base);
      b[0] = f2bf(v.x); b[1] = f2bf(v.y); b[2] = f2bf(v.z); b[3] = f2bf(v.w);
    } else {
      const ushort4 v = *(const ushort4*)((const u16*)in + base);
      b[0] = v.x; b[1] = v.y; b[2] = v.z; b[3] = v.w;
    }
#pragma unroll
    for (int j = 0; j < 4; ++j) tile[c4 * 4 + j][i * 16 + r_in] = b[j];
  }
  __syncthreads();
  const int c_loc = t >> 3, r8 = t & 7;
#pragma unroll
  for (int i = 0; i < 2; ++i) {
    const int c = c_loc + i * 32;
    *(short8*)(out + zoff + (size_t)(c0 + c) * R + r0 + r8 * 8) =
        *(const short8*)(&tile[c][r8 * 8]);
  }
}

// ---------- split-K reduce: xE[b][j] = bf16(sum_s P[(b*4+s)*stride + j]) ----------
__global__ void reduce_splitk(const float* __restrict__ P, u16* __restrict__ out) {
  const int b = blockIdx.y;
  const int j = (blockIdx.x * 256 + threadIdx.x) * 8;
  const float* p = P + (size_t)b * 4 * 524288 + j;
  float acc[8] = {};
#pragma unroll
  for (int s = 0; s < 4; ++s) {
    const float4 v0 = *(const float4*)(p + (size_t)s * 524288);
    const float4 v1 = *(const float4*)(p + (size_t)s * 524288 + 4);
    acc[0] += v0.x; acc[1] += v0.y; acc[2] += v0.z; acc[3] += v0.w;
    acc[4] += v1.x; acc[5] += v1.y; acc[6] += v1.z; acc[7] += v1.w;
  }
  union { u16 s[8]; short8 v; } o;
#pragma unroll
  for (int k = 0; k < 8; ++k) o.s[k] = f2bf(acc[k]);
  *(short8*)(out + (size_t)b * 524288 + j) = o.v;
}

// ---------- 128x128-tile GEMM (small/batched shapes): r9 3-buffer pipeline, PASSED ----------
template <int MODE>
__global__ void __launch_bounds__(256) gemm_bt(const u16* __restrict__ A0, const u16* __restrict__ Bt0,
                                               const void* __restrict__ bias, void* __restrict__ Cv,
                                               const int* __restrict__ flag, int M, int N, int K,
                                               int ldA, int ldB, size_t sA, size_t sB, size_t sC) {
  __shared__ __align__(16) u16 As[3][128 * 32];
  __shared__ __align__(16) u16 Bs[3][128 * 32];

  const int gx = gridDim.x, gy = gridDim.y;
  const int gxy = gx * gy;
  const int nwg = gxy * gridDim.z;
  int lin = (blockIdx.z * gy + blockIdx.y) * gx + blockIdx.x;
  if ((nwg & 7) == 0) lin = (lin & 7) * (nwg >> 3) + (lin >> 3);
  const int bz = lin / gxy;
  const int rem = lin - bz * gxy;
  const int by = rem / gx;
  const int bx = rem - by * gx;

  const int z = bz;
  const int bb = (MODE == 2) ? (z >> 2) : z;
  const int kstart = (MODE == 2) ? ((z & 3) * K) : 0;
  const u16* A = A0 + (size_t)bb * sA;
  const u16* Bt = Bt0 + (size_t)bb * sB;
  const int tid = threadIdx.x;
  const int wid = tid >> 6, lane = tid & 63;
  const int wm = wid >> 1, wn = wid & 1;
  const int quad = lane >> 4, l16 = lane & 15;
  const int m0 = by * 128, n0 = bx * 128;

  const int srow = lane >> 2;
  const int scol = (((lane & 3) ^ ((lane >> 3) & 3)) * 8);   // elements

  const u16* Ag = A + (size_t)(m0 + srow) * ldA + scol + kstart;
  const u16* Bg = Bt + (size_t)(n0 + srow) * ldB + scol + kstart;

  f32x4 acc[4][4] = {};

  auto stage = [&](int buf, int k0) {
#pragma unroll
    for (int r = 0; r < 2; ++r) {
      const int rowb = r * 64 + wid * 16;               // wave-uniform LDS base
      gl2lds16(Ag + (size_t)rowb * ldA + k0, &As[buf][rowb * 32]);
      gl2lds16(Bg + (size_t)rowb * ldB + k0, &Bs[buf][rowb * 32]);
    }
  };

  const int nI = K >> 5;
  stage(0, 0);
  stage(1, 32);

  const int rslot = (quad ^ ((l16 >> 1) & 3)) * 8;      // elements

  int cur = 0;                                          // t % 3
  for (int t = 0; t < nI; ++t) {
    if (t + 1 < nI) {
      asm volatile("s_waitcnt lgkmcnt(0) vmcnt(4)" ::: "memory");
    } else {
      asm volatile("s_waitcnt lgkmcnt(0) vmcnt(0)" ::: "memory");
    }
    SBAR();
    __builtin_amdgcn_s_barrier();                       // tile-t DMA globally done; buf free
    SBAR();

    const int nxt = (cur + 2 >= 3) ? (cur - 1) : (cur + 2);
    if (t + 2 < nI) stage(nxt, (t + 2) << 5);           // overwrite buffer read at t-1

    short8 a[4], b[4];
#pragma unroll
    for (int mi = 0; mi < 4; ++mi)
      a[mi] = *(const short8*)(&As[cur][(wm * 64 + mi * 16 + l16) * 32 + rslot]);
#pragma unroll
    for (int ni = 0; ni < 4; ++ni)
      b[ni] = *(const short8*)(&Bs[cur][(wn * 64 + ni * 16 + l16) * 32 + rslot]);
    __builtin_amdgcn_s_setprio(1);
#pragma unroll
    for (int mi = 0; mi < 4; ++mi)
#pragma unroll
      for (int ni = 0; ni < 4; ++ni)
        acc[mi][ni] = __builtin_amdgcn_mfma_f32_16x16x32_bf16(a[mi], b[ni], acc[mi][ni], 0, 0, 0);
    __builtin_amdgcn_s_setprio(0);

    cur = (cur + 1 >= 3) ? 0 : (cur + 1);
  }

  const bool f32out = (MODE == 1) && (*flag != 0);
  float* Pz = (MODE == 2) ? ((float*)Cv + (size_t)z * M * N) : nullptr;
#pragma unroll
  for (int mi = 0; mi < 4; ++mi) {
#pragma unroll
    for (int ni = 0; ni < 4; ++ni) {
      const int mloc = wm * 64 + mi * 16 + quad * 4;
      const int n = n0 + wn * 64 + ni * 16 + l16;
      float badd = 0.0f;
      if (MODE == 1)
        badd = f32out ? ((const float*)bias)[n] : bf2f(((const u16*)bias)[n]);
#pragma unroll
      for (int r = 0; r < 4; ++r) {
        if (MODE == 2) {
          Pz[(size_t)(m0 + mloc + r) * N + n] = acc[mi][ni][r];
        } else {
          const size_t oi = (size_t)bb * sC + (size_t)(m0 + mloc + r) * N + n;
          if (f32out) ((float*)Cv)[oi] = acc[mi][ni][r] + badd;
          else        ((u16*)Cv)[oi]  = f2bf(acc[mi][ni][r] + badd);
        }
      }
    }
  }
}

// ---------- 256x256-tile GEMM, BK=32, 512 threads (8 waves 2Mx4N), 2 LDS buffers ----------
// r11-PASSED configuration (best measured total): grid (4,64), 64 KB LDS.
template <int MODE>
__global__ void __launch_bounds__(512, 2) gemm256(const u16* __restrict__ A,
                                                  const u16* __restrict__ Bt,
                                                  const void* __restrict__ bias,
                                                  void* __restrict__ Cv,
                                                  const int* __restrict__ flag,
                                                  int M, int N, int K) {
  __shared__ __align__(16) u16 As[2][256 * 32];        // 2 x 16 KB
  __shared__ __align__(16) u16 Bs[2][256 * 32];        // 2 x 16 KB -> 64 KB total

  const int gx = gridDim.x;                             // N/256
  const int nwg = gx * gridDim.y;
  int lin = blockIdx.y * gx + blockIdx.x;
  if ((nwg & 7) == 0) lin = (lin & 7) * (nwg >> 3) + (lin >> 3);
  const int by = lin / gx;
  const int bx = lin - by * gx;
  const int m0 = by * 256, n0 = bx * 256;

  const int tid = threadIdx.x;
  const int wid = tid >> 6, lane = tid & 63;
  const int wm = wid >> 2, wn = wid & 3;                // 2 x 4 wave grid
  const int quad = lane >> 4, l16 = lane & 15;

  const int stR = wid * 16 + (lane >> 2);
  const int sgs = ((lane & 3) ^ ((lane >> 3) & 3)) * 8; // pre-swizzled source col (elems)
  const u16* AgS = A + (size_t)(m0 + stR) * K + sgs;
  const u16* BgS = Bt + (size_t)(n0 + stR) * K + sgs;

  auto stage = [&](int buf, int tk) {
    const int kof = tk * 32;
#pragma unroll
    for (int e = 0; e < 2; ++e) {
      const int rowb = e * 128 + wid * 16;              // wave-uniform LDS row base
      gl2lds16(AgS + (size_t)(e * 128) * K + kof, &As[buf][rowb * 32]);
      gl2lds16(BgS + (size_t)(e * 128) * K + kof, &Bs[buf][rowb * 32]);
    }
  };

  f32x4 acc[8][4] = {};                                 // 128 VGPR accumulator
  const int nT = K >> 5;

  stage(0, 0);
  stage(1, 1);

  const int rslot = (quad ^ ((l16 >> 1) & 3)) * 8;      // elements

  for (int t = 0; t < nT; ++t) {
    const int cur = t & 1;
    if (t + 1 < nT) {
      asm volatile("s_waitcnt vmcnt(4)" ::: "memory");  // own tile-t loads done
    } else {
      asm volatile("s_waitcnt vmcnt(0)" ::: "memory");  // last tile: drain all
    }
    SBAR();
    __builtin_amdgcn_s_barrier();                       // all waves' tile-t DMA landed
    SBAR();

    short8 bf[4];
#pragma unroll
    for (int nf = 0; nf < 4; ++nf)
      bf[nf] = *(const short8*)(&Bs[cur][(wn * 64 + nf * 16 + l16) * 32 + rslot]);
#pragma unroll
    for (int mf = 0; mf < 8; ++mf) {
      const short8 af = *(const short8*)(&As[cur][(wm * 128 + mf * 16 + l16) * 32 + rslot]);
      __builtin_amdgcn_s_setprio(1);
#pragma unroll
      for (int nf = 0; nf < 4; ++nf)
        acc[mf][nf] = __builtin_amdgcn_mfma_f32_16x16x32_bf16(af, bf[nf], acc[mf][nf], 0, 0, 0);
      __builtin_amdgcn_s_setprio(0);
    }

    asm volatile("s_waitcnt lgkmcnt(0)" ::: "memory");  // my ds_reads of buf(cur) done
    SBAR();
    __builtin_amdgcn_s_barrier();                       // everyone done reading buf(cur)
    if (t + 2 < nT) stage(cur, t + 2);                  // overwrite freed buffer
  }

  const bool f32out = (MODE == 1) && (*flag != 0);
#pragma unroll
  for (int mf = 0; mf < 8; ++mf) {
#pragma unroll
    for (int nf = 0; nf < 4; ++nf) {
      const int row = m0 + wm * 128 + mf * 16 + quad * 4;
      const int col = n0 + wn * 64 + nf * 16 + l16;
      float badd = 0.0f;
      if (MODE == 1)
        badd = f32out ? ((const float*)bias)[col] : bf2f(((const u16*)bias)[col]);
#pragma unroll
      for (int r = 0; r < 4; ++r) {
        const size_t oi = (size_t)(row + r) * N + col;
        if (MODE == 1) {
          if (f32out) ((float*)Cv)[oi] = acc[mf][nf][r] + badd;
          else        ((u16*)Cv)[oi]  = f2bf(acc[mf][nf][r] + badd);
        } else {
          ((u16*)Cv)[oi] = f2bf(acc[mf][nf][r]);
        }
      }
    }
  }
}

// ---------- fused scores+softmax+ctx, block-cooperative K/V LDS staging (r7, proven) ----------
__global__ void __launch_bounds__(256, 2) attn_fused(const u16* Q, const u16* __restrict__ Kp,
                                                     const u16* __restrict__ VpT, u16* Ctx) {
  __shared__ __align__(16) u16 Ks[KPROJ * DKH];     // [256][64] u16, swizzled cols
  __shared__ __align__(16) u16 Vs[DKH * KPROJ];     // [64][256] u16, swizzled cols
  __shared__ __align__(16) u16 Ps[4 * 32 * 36];
  __shared__ __align__(16) float invS[4 * 32];

  int lin = blockIdx.y * gridDim.x + blockIdx.x;    // grid (32, 64): 2048 blocks
  lin = (lin & 7) * 256 + (lin >> 3);               // XCD x -> bh in [8x, 8x+8)
  const int bx = lin & 31;
  const int bh = lin >> 5;
  const int b = bh >> 4, h = bh & 15;
  const int tid = threadIdx.x, wid = tid >> 6, lane = tid & 63;
  const int quad = lane >> 4, l16 = lane & 15;
  const int t0 = bx * 128 + wid * 32;
  const u16* Qb = Q + ((size_t)b * T_SEQ + t0) * DMODEL + h * DKH;
  const u16* Kpb = Kp + (size_t)b * (KPROJ * DMODEL) + h * DKH;
  const u16* Vpb = VpT + (size_t)b * (DMODEL * KPROJ) + (size_t)(h * DKH) * KPROJ;
  u16* PsW = Ps + wid * (32 * 36);
  float* invW = invS + wid * 32;

  {
    const int srow = lane >> 3;                          // 0..7 within issue
    const int scolb = ((lane & 7) * 16) ^ ((srow & 7) << 4);   // inverse swizzle on source
#pragma unroll
    for (int i = 0; i < 8; ++i) {
      const int rbase = wid * 64 + i * 8;
      gl2lds16(Kpb + (size_t)(rbase + srow) * DMODEL + (scolb >> 1), Ks + rbase * DKH);
    }
    const int vrow = lane >> 5;                          // 0..1 within issue
#pragma unroll
    for (int j = 0; j < 8; ++j) {
      const int dbase = wid * 16 + j * 2;
      const int d = dbase + vrow;
      const int vcolb = ((lane & 31) * 16) ^ ((d & 7) << 4);
      gl2lds16(Vpb + (size_t)d * KPROJ + (vcolb >> 1), Vs + dbase * KPROJ);
    }
  }

  short8 q[2][2];
#pragma unroll
  for (int kk = 0; kk < 2; ++kk) {
    q[kk][0] = *(const short8*)(Qb + (size_t)l16 * DMODEL + kk * 32 + quad * 8);
    q[kk][1] = *(const short8*)(Qb + (size_t)(16 + l16) * DMODEL + kk * 32 + quad * 8);
  }

  __syncthreads();   // drains vmcnt incl. LDS-DMA; K/V ready

  f32x4 c0[4] = {}, c1[4] = {};
  float sm0 = 0.0f, sm1 = 0.0f;
  const float sc = 0.125f * 1.44269504f;   // 1/sqrt(64) * log2(e)

#pragma unroll
  for (int kt = 0; kt < 8; ++kt) {
    short8 kf[2][2];
#pragma unroll
    for (int m = 0; m < 2; ++m)
#pragma unroll
      for (int k2 = 0; k2 < 2; ++k2) {
        const int row = kt * 32 + m * 16 + l16;
        const int off = ((k2 * 64 + quad * 16) ^ ((row & 7) << 4)) >> 1;
        kf[m][k2] = *(const short8*)(Ks + row * DKH + off);
      }
    f32x4 st[2][2] = {};
    __builtin_amdgcn_s_setprio(1);
#pragma unroll
    for (int m = 0; m < 2; ++m)
#pragma unroll
      for (int k2 = 0; k2 < 2; ++k2) {
        st[m][0] = __builtin_amdgcn_mfma_f32_16x16x32_bf16(kf[m][k2], q[k2][0], st[m][0], 0, 0, 0);
        st[m][1] = __builtin_amdgcn_mfma_f32_16x16x32_bf16(kf[m][k2], q[k2][1], st[m][1], 0, 0, 0);
      }
    __builtin_amdgcn_s_setprio(0);

#pragma unroll
    for (int m = 0; m < 2; ++m) {
      const float a0 = exp2f(st[m][0][0] * sc), a1 = exp2f(st[m][0][1] * sc);
      const float a2 = exp2f(st[m][0][2] * sc), a3 = exp2f(st[m][0][3] * sc);
      const float b0 = exp2f(st[m][1][0] * sc), b1 = exp2f(st[m][1][1] * sc);
      const float b2 = exp2f(st[m][1][2] * sc), b3 = exp2f(st[m][1][3] * sc);
      sm0 += (a0 + a1) + (a2 + a3);
      sm1 += (b0 + b1) + (b2 + b3);
      *(uint2*)(PsW + l16 * 36 + m * 16 + quad * 4) =
          make_uint2(cvt_pk_bf16(a0, a1), cvt_pk_bf16(a2, a3));
      *(uint2*)(PsW + (16 + l16) * 36 + m * 16 + quad * 4) =
          make_uint2(cvt_pk_bf16(b0, b1), cvt_pk_bf16(b2, b3));
    }

    short8 vf[4];
#pragma unroll
    for (int ni = 0; ni < 4; ++ni) {
      const int d = ni * 16 + l16;
      const int off = ((kt * 64 + quad * 16) ^ ((d & 7) << 4)) >> 1;
      vf[ni] = *(const short8*)(Vs + d * KPROJ + off);
    }
    short8 pa0 = *(const short8*)(PsW + (size_t)l16 * 36 + quad * 8);
    short8 pa1 = *(const short8*)(PsW + (size_t)(16 + l16) * 36 + quad * 8);
    __builtin_amdgcn_s_setprio(1);
#pragma unroll
    for (int ni = 0; ni < 4; ++ni) {
      c0[ni] = __builtin_amdgcn_mfma_f32_16x16x32_bf16(pa0, vf[ni], c0[ni], 0, 0, 0);
      c1[ni] = __builtin_amdgcn_mfma_f32_16x16x32_bf16(pa1, vf[ni], c1[ni], 0, 0, 0);
    }
    __builtin_amdgcn_s_setprio(0);
  }

  sm0 += __shfl_xor(sm0, 16); sm0 += __shfl_xor(sm0, 32);
  sm1 += __shfl_xor(sm1, 16); sm1 += __shfl_xor(sm1, 32);
  if (quad == 0) {
    invW[l16] = 1.0f / sm0;
    invW[16 + l16] = 1.0f / sm1;
  }

  const float4 iv0 = *(const float4*)(invW + quad * 4);
  const float4 iv1 = *(const float4*)(invW + 16 + quad * 4);
  const float ivr0[4] = {iv0.x, iv0.y, iv0.z, iv0.w};
  const float ivr1[4] = {iv1.x, iv1.y, iv1.z, iv1.w};
#pragma unroll
  for (int ni = 0; ni < 4; ++ni)
#pragma unroll
    for (int r = 0; r < 4; ++r) {
      Ctx[((size_t)b * T_SEQ + t0 + quad * 4 + r) * DMODEL + h * DKH + ni * 16 + l16] =
          f2bf(c0[ni][r] * ivr0[r]);
      Ctx[((size_t)b * T_SEQ + t0 + 16 + quad * 4 + r) * DMODEL + h * DKH + ni * 16 + l16] =
          f2bf(c1[ni][r] * ivr1[r]);
    }
}

extern "C" void kernel_launch(void* const* d_in, const int* in_sizes, int n_in,
                              void* d_out, int out_size, void* d_ws, size_t ws_size,
                              hipStream_t stream) {
  (void)in_sizes; (void)n_in; (void)out_size; (void)ws_size;

  int* flag = (int*)d_ws;
  u16* base = (u16*)d_ws + 16;
  const size_t WSZ = 1048576;        // 1024*1024
  const size_t XSZ = 16777216;       // 4*4096*1024
  u16* wqT   = base + 0 * WSZ;
  u16* wkT   = base + 1 * WSZ;
  u16* wvT   = base + 2 * WSZ;
  u16* woT   = base + 3 * WSZ;
  u16* ekevT = base + 4 * WSZ;       // [ekT(256x4096); evT(256x4096)]
  u16* xT    = base + 6 * WSZ;       // (4, 1024, 4096)
  u16* xE    = xT + XSZ;             // (4, 512, 1024): rows 0-255 = Ek^T x, 256-511 = Ev^T x
  u16* Kp    = xE + 4 * 524288;      // (4, 256, 1024)
  u16* VpT   = Kp + 4 * 262144;      // (4, 1024, 256)
  u16* Q     = VpT + 4 * 262144;     // (4, 4096, 1024); also split-K partial buffer (32 MiB), then ctx
  u16* xbf   = (u16*)d_out;          // x bf16 scratch in d_out (dead before final gemm)
  float* xEp = (float*)Q;            // 16 blocks of 512*1024 fp32 partials (exactly Q's 32 MiB)

  sniff_dtype<<<1, 64, 0, stream>>>((const u16*)d_in[0], flag);

  // x: transpose (xT) + fused row-major bf16 copy (xbf), 64x64 tiles, 16B/lane
  transpose64_x<<<dim3(16, 64, 4), 256, 0, stream>>>(d_in[0], xT, xbf, flag);
  // 4 weight transposes in one launch (outputs contiguous at base+z*WSZ)
  transpose64_m<<<dim3(16, 16, 4), 256, 0, stream>>>(d_in[1], d_in[2], d_in[3], d_in[6],
                                                     wqT, 1024, 1024, flag);
  // Ek/Ev transposes in one launch (outputs contiguous)
  transpose64_m<<<dim3(4, 64, 2), 256, 0, stream>>>(d_in[4], d_in[5], nullptr, nullptr,
                                                    ekevT, 4096, 256, flag);

  // xE[b] = [Ek;Ev]^T @ x[b], split-K x4: z = b*4+s, each K-chunk 1024
  gemm_bt<2><<<dim3(8, 4, 16), 256, 0, stream>>>(ekevT, xT, nullptr, xEp, flag,
                                                 512, 1024, 1024, 4096, 4096,
                                                 0, (size_t)DMODEL * T_SEQ, 0);
  reduce_splitk<<<dim3(256, 4), 256, 0, stream>>>(xEp, xE);

  // Kp[b] = xEk[b] @ Wk -> (256 x 1024)
  gemm_bt<0><<<dim3(8, 2, 4), 256, 0, stream>>>(xE, wkT, nullptr, Kp, flag,
                                                256, 1024, 1024, 1024, 1024, 524288, 0, 262144);
  // Vp^T[b] = Wv^T @ xEv[b]^T -> (1024 x 256)
  gemm_bt<0><<<dim3(2, 8, 4), 256, 0, stream>>>(wvT, xE + 262144, nullptr, VpT, flag,
                                                1024, 256, 1024, 1024, 1024, 0, 524288, 262144);
  // Q = x @ Wq -> (16384 x 1024), 256^2-tile pipeline (r11 config)
  gemm256<0><<<dim3(4, 64), 512, 0, stream>>>(xbf, wqT, nullptr, Q, flag, 16384, 1024, 1024);

  attn_fused<<<dim3(32, 64), 256, 0, stream>>>(Q, Kp, VpT, Q /*ctx in-place*/);

  // out = ctx @ Wo + bo (fp32 or bf16 per flag), 256^2-tile pipeline (r11 config)
  gemm256<1><<<dim3(4, 64), 512, 0, stream>>>(Q, woT, d_in[7], d_out, flag, 16384, 1024, 1024);
}